// Round 1
// baseline (102.751 us; speedup 1.0000x reference)
//
#include <hip/hip_runtime.h>
#include <math.h>

#define NN 3072
#define FEAT 512
#define NH 8
#define ND 8
#define HD 64           // NH*ND
#define NE 100000
#define NC 2
#define ALPHA 0.2f
#define CAP 96          // max neighbors per row (mean ~7, Poisson tail at 96 ~ 0)
#define K5_BLOCKS 512

// K0: transpose W [H,FEAT,D] -> Wt [FEAT, HD]  (for coalesced GEMM reads)
__global__ void k_transpose_w(const float* __restrict__ W, float* __restrict__ Wt) {
    int idx = blockIdx.x * blockDim.x + threadIdx.x;
    if (idx >= FEAT * HD) return;
    int f = idx / HD, hd = idx % HD;
    int h = hd >> 3, d = hd & 7;
    Wt[idx] = W[h * FEAT * ND + f * ND + d];
}

// K1: Wh[n, h*8+d] = sum_f x[n,f] * W[h,f,d];  s1[h,n] = Wh.a1, s2[h,n] = Wh.a2
__global__ __launch_bounds__(64) void k_wh(const float* __restrict__ x, const float* __restrict__ Wt,
                                           const float* __restrict__ a1, const float* __restrict__ a2,
                                           float* __restrict__ Wh, float* __restrict__ s1,
                                           float* __restrict__ s2) {
    __shared__ float xs[FEAT];
    int n = blockIdx.x;
    int l = threadIdx.x;           // l = h*8+d
    for (int f = l; f < FEAT; f += 64) xs[f] = x[n * FEAT + f];
    __syncthreads();
    float acc = 0.f;
    for (int f = 0; f < FEAT; ++f) acc = fmaf(xs[f], Wt[f * HD + l], acc);
    Wh[n * HD + l] = acc;
    float t1 = acc * a1[l];
    float t2 = acc * a2[l];
    for (int m = 1; m < 8; m <<= 1) {  // reduce over d within the 8-lane head group
        t1 += __shfl_xor(t1, m, 64);
        t2 += __shfl_xor(t2, m, 64);
    }
    if ((l & 7) == 0) {
        int h = l >> 3;
        s1[h * NN + n] = t1;
        s2[h * NN + n] = t2;
    }
}

// K2: compact adj row i into ordered neighbor list (deterministic ballot scan)
__global__ __launch_bounds__(64) void k_nbr(const float* __restrict__ adj, int* __restrict__ nbr,
                                            int* __restrict__ cnt) {
    int i = blockIdx.x;
    int lane = threadIdx.x;
    int base = 0;
    for (int j0 = 0; j0 < NN; j0 += 64) {
        int j = j0 + lane;
        bool nz = adj[(size_t)i * NN + j] > 0.f;
        unsigned long long m = __ballot(nz);
        if (nz) {
            int pos = base + __popcll(m & ((1ull << lane) - 1ull));
            if (pos < CAP) nbr[i * CAP + pos] = j;
        }
        base += __popcll(m);
    }
    if (lane == 0) cnt[i] = base < CAP ? base : CAP;
}

// K3: per (i) wave: online softmax over neighbors, weighted sum of Wh, ELU -> emb
__global__ __launch_bounds__(256) void k_attn(const float* __restrict__ Wh, const float* __restrict__ s1,
                                              const float* __restrict__ s2, const int* __restrict__ nbr,
                                              const int* __restrict__ cnt, float* __restrict__ emb) {
    int wid = threadIdx.x >> 6;
    int lane = threadIdx.x & 63;   // lane = h*8+d
    int i = blockIdx.x * 4 + wid;
    int h = lane >> 3;
    float s1i = s1[h * NN + i];
    int ni = cnt[i];
    float m = -INFINITY, denom = 0.f, acc = 0.f;
    for (int k = 0; k < ni; ++k) {
        int j = nbr[i * CAP + k];
        float ev = s1i + s2[h * NN + j];
        ev = ev > 0.f ? ev : ALPHA * ev;
        float mn = fmaxf(m, ev);
        float c = __expf(m - mn);      // exp(-inf)=0 on first iter
        float p = __expf(ev - mn);
        denom = denom * c + p;
        acc = acc * c + p * Wh[j * HD + lane];
        m = mn;
    }
    float o = acc / denom;
    o = o > 0.f ? o : expm1f(o);       // ELU
    emb[i * HD + lane] = o;
}

// K4: P[n] = emb[n] @ W1[0:64] + b1;  Q[n] = emb[n] @ W1[64:128]
__global__ __launch_bounds__(64) void k_pq(const float* __restrict__ emb, const float* __restrict__ W1,
                                           const float* __restrict__ b1, float* __restrict__ P,
                                           float* __restrict__ Q) {
    __shared__ float es[HD];
    int n = blockIdx.x;
    int j = threadIdx.x;
    es[j] = emb[n * HD + j];
    __syncthreads();
    float p = b1[j], q = 0.f;
    for (int k = 0; k < HD; ++k) {
        p = fmaf(es[k], W1[k * HD + j], p);
        q = fmaf(es[k], W1[(HD + k) * HD + j], q);
    }
    P[n * HD + j] = p;
    Q[n * HD + j] = q;
}

// K5: per-edge: h1 = relu(P[L]+Q[R]); logits = h1@W2 + b2; nll; per-block partial sums
__global__ __launch_bounds__(256) void k_cls(const float* __restrict__ P, const float* __restrict__ Q,
                                             const int* __restrict__ L, const int* __restrict__ R,
                                             const int* __restrict__ label, const float* __restrict__ W2,
                                             const float* __restrict__ b2, float* __restrict__ partials) {
    int wid = threadIdx.x >> 6;
    int lane = threadIdx.x & 63;
    int gw = blockIdx.x * 4 + wid;
    int nw = gridDim.x * 4;
    float w20 = W2[lane * 2 + 0];
    float w21 = W2[lane * 2 + 1];
    float b20 = b2[0], b21 = b2[1];
    float sum = 0.f;
    for (int e = gw; e < NE; e += nw) {
        int ln = L[e], rn = R[e];
        float v = P[ln * HD + lane] + Q[rn * HD + lane];
        v = fmaxf(v, 0.f);
        float t0 = v * w20, t1 = v * w21;
        for (int m = 1; m < 64; m <<= 1) {   // butterfly: all lanes end with full sums
            t0 += __shfl_xor(t0, m, 64);
            t1 += __shfl_xor(t1, m, 64);
        }
        float l0 = t0 + b20, l1 = t1 + b21;
        float mx = fmaxf(l0, l1);
        float lse = mx + __logf(__expf(l0 - mx) + __expf(l1 - mx));
        float sel = label[e] ? l1 : l0;
        sum += lse - sel;
    }
    __shared__ float wsum[4];
    if (lane == 0) wsum[wid] = sum;
    __syncthreads();
    if (threadIdx.x == 0) partials[blockIdx.x] = wsum[0] + wsum[1] + wsum[2] + wsum[3];
}

// K6: reduce partials -> mean
__global__ __launch_bounds__(512) void k_reduce(const float* __restrict__ partials, float* __restrict__ out) {
    __shared__ float sh[K5_BLOCKS];
    int t = threadIdx.x;
    sh[t] = partials[t];
    __syncthreads();
    for (int s = K5_BLOCKS / 2; s > 0; s >>= 1) {
        if (t < s) sh[t] += sh[t + s];
        __syncthreads();
    }
    if (t == 0) out[0] = sh[0] / (float)NE;
}

extern "C" void kernel_launch(void* const* d_in, const int* in_sizes, int n_in,
                              void* d_out, int out_size, void* d_ws, size_t ws_size,
                              hipStream_t stream) {
    const float* x     = (const float*)d_in[0];
    const float* adj   = (const float*)d_in[1];
    const int*   L     = (const int*)d_in[2];
    const int*   R     = (const int*)d_in[3];
    const int*   label = (const int*)d_in[4];
    const float* W     = (const float*)d_in[5];
    const float* a1    = (const float*)d_in[6];
    const float* a2    = (const float*)d_in[7];
    const float* W1    = (const float*)d_in[8];
    const float* b1    = (const float*)d_in[9];
    const float* W2    = (const float*)d_in[10];
    const float* b2    = (const float*)d_in[11];

    char* ws = (char*)d_ws;
    float* Wt       = (float*)(ws + 0);         //  131072 B
    float* Wh       = (float*)(ws + 131072);    //  786432 B
    float* s1       = (float*)(ws + 917504);    //   98304 B
    float* s2       = (float*)(ws + 1015808);   //   98304 B
    int*   cnt      = (int*)  (ws + 1114112);   //   12288 B
    int*   nbr      = (int*)  (ws + 1126400);   // 1179648 B
    float* emb      = (float*)(ws + 2306048);   //  786432 B
    float* P        = (float*)(ws + 3092480);   //  786432 B
    float* Q        = (float*)(ws + 3878912);   //  786432 B
    float* partials = (float*)(ws + 4665344);   //    2048 B  -> total 4667392 B

    k_transpose_w<<<(FEAT * HD + 255) / 256, 256, 0, stream>>>(W, Wt);
    k_wh<<<NN, 64, 0, stream>>>(x, Wt, a1, a2, Wh, s1, s2);
    k_nbr<<<NN, 64, 0, stream>>>(adj, nbr, cnt);
    k_attn<<<NN / 4, 256, 0, stream>>>(Wh, s1, s2, nbr, cnt, emb);
    k_pq<<<NN, 64, 0, stream>>>(emb, W1, b1, P, Q);
    k_cls<<<K5_BLOCKS, 256, 0, stream>>>(P, Q, L, R, label, W2, b2, partials);
    k_reduce<<<1, K5_BLOCKS, 0, stream>>>(partials, (float*)d_out);
}

// Round 2
// 83.760 us; speedup vs baseline: 1.2267x; 1.2267x over previous
//
#include <hip/hip_runtime.h>
#include <math.h>

#define NN 3072
#define FEAT 512
#define NH 8
#define ND 8
#define HD 64           // NH*ND
#define NE 100000
#define NC 2
#define ALPHA 0.2f
#define CAP 96          // max neighbors per row (mean ~7)
#define K5_BLOCKS 2048
#define WH_ROWS 4

// K0: transpose W [H,FEAT,D] -> Wt [FEAT, HD]  (for coalesced GEMM reads)
__global__ void k_transpose_w(const float* __restrict__ W, float* __restrict__ Wt) {
    int idx = blockIdx.x * blockDim.x + threadIdx.x;
    if (idx >= FEAT * HD) return;
    int f = idx / HD, hd = idx % HD;
    int h = hd >> 3, d = hd & 7;
    Wt[idx] = W[h * FEAT * ND + f * ND + d];
}

// K1: Wh[n, h*8+d] = sum_f x[n,f] * W[h,f,d];  s1[h,n]=Wh.a1, s2[h,n]=Wh.a2
//     4 rows per wave: one Wt load feeds 4 fmas (4x less L2 traffic, 4-way ILP)
__global__ __launch_bounds__(64) void k_wh(const float* __restrict__ x, const float* __restrict__ Wt,
                                           const float* __restrict__ a1, const float* __restrict__ a2,
                                           float* __restrict__ Wh, float* __restrict__ s1,
                                           float* __restrict__ s2) {
    __shared__ float xs[WH_ROWS][FEAT];
    int n0 = blockIdx.x * WH_ROWS;
    int l = threadIdx.x;           // l = h*8+d
    for (int r = 0; r < WH_ROWS; ++r)
        for (int f = l; f < FEAT; f += 64)
            xs[r][f] = x[(n0 + r) * FEAT + f];
    __syncthreads();
    float acc[WH_ROWS] = {0.f, 0.f, 0.f, 0.f};
    #pragma unroll 4
    for (int f = 0; f < FEAT; ++f) {
        float wt = Wt[f * HD + l];
        #pragma unroll
        for (int r = 0; r < WH_ROWS; ++r) acc[r] = fmaf(xs[r][f], wt, acc[r]);
    }
    float va1 = a1[l], va2 = a2[l];
    #pragma unroll
    for (int r = 0; r < WH_ROWS; ++r) {
        int n = n0 + r;
        Wh[n * HD + l] = acc[r];
        float t1 = acc[r] * va1;
        float t2 = acc[r] * va2;
        for (int m = 1; m < 8; m <<= 1) {
            t1 += __shfl_xor(t1, m, 64);
            t2 += __shfl_xor(t2, m, 64);
        }
        if ((l & 7) == 0) {
            int h = l >> 3;
            s1[h * NN + n] = t1;
            s2[h * NN + n] = t2;
        }
    }
}

// K2: compact adj row i into neighbor list (float4 loads; deterministic ballot scan)
__global__ __launch_bounds__(64) void k_nbr(const float* __restrict__ adj, int* __restrict__ nbr,
                                            int* __restrict__ cnt) {
    int i = blockIdx.x;
    int lane = threadIdx.x;
    unsigned long long lmask = (1ull << lane) - 1ull;
    int base = 0;
    for (int j0 = 0; j0 < NN; j0 += 256) {
        float4 v = *(const float4*)&adj[(size_t)i * NN + j0 + lane * 4];
        #pragma unroll
        for (int k = 0; k < 4; ++k) {
            float vk = k == 0 ? v.x : k == 1 ? v.y : k == 2 ? v.z : v.w;
            bool nz = vk > 0.f;
            unsigned long long m = __ballot(nz);
            if (nz) {
                int pos = base + __popcll(m & lmask);
                if (pos < CAP) nbr[i * CAP + pos] = j0 + lane * 4 + k;
            }
            base += __popcll(m);
        }
    }
    if (lane == 0) cnt[i] = base < CAP ? base : CAP;
}

// K3: per (i) wave: online softmax over neighbors, weighted sum of Wh, ELU -> emb
__global__ __launch_bounds__(256) void k_attn(const float* __restrict__ Wh, const float* __restrict__ s1,
                                              const float* __restrict__ s2, const int* __restrict__ nbr,
                                              const int* __restrict__ cnt, float* __restrict__ emb) {
    int wid = threadIdx.x >> 6;
    int lane = threadIdx.x & 63;   // lane = h*8+d
    int i = blockIdx.x * 4 + wid;
    int h = lane >> 3;
    float s1i = s1[h * NN + i];
    int ni = cnt[i];
    float m = -INFINITY, denom = 0.f, acc = 0.f;
    for (int k = 0; k < ni; ++k) {
        int j = nbr[i * CAP + k];
        float ev = s1i + s2[h * NN + j];
        ev = ev > 0.f ? ev : ALPHA * ev;
        float mn = fmaxf(m, ev);
        float c = __expf(m - mn);      // exp(-inf)=0 on first iter
        float p = __expf(ev - mn);
        denom = denom * c + p;
        acc = acc * c + p * Wh[j * HD + lane];
        m = mn;
    }
    float o = acc / denom;
    o = o > 0.f ? o : expm1f(o);       // ELU
    emb[i * HD + lane] = o;
}

// K4: P[n] = emb[n] @ W1[0:64] + b1;  Q[n] = emb[n] @ W1[64:128]
__global__ __launch_bounds__(64) void k_pq(const float* __restrict__ emb, const float* __restrict__ W1,
                                           const float* __restrict__ b1, float* __restrict__ P,
                                           float* __restrict__ Q) {
    __shared__ float es[HD];
    int n = blockIdx.x;
    int j = threadIdx.x;
    es[j] = emb[n * HD + j];
    __syncthreads();
    float p = b1[j], q = 0.f;
    for (int k = 0; k < HD; ++k) {
        p = fmaf(es[k], W1[k * HD + j], p);
        q = fmaf(es[k], W1[(HD + k) * HD + j], q);
    }
    P[n * HD + j] = p;
    Q[n * HD + j] = q;
}

// K5: 16 lanes per edge, float4 loads. h1 = relu(P[L]+Q[R]); logits = h1@W2+b2; nll.
__global__ __launch_bounds__(256) void k_cls(const float* __restrict__ P, const float* __restrict__ Q,
                                             const int* __restrict__ L, const int* __restrict__ R,
                                             const int* __restrict__ label, const float* __restrict__ W2,
                                             const float* __restrict__ b2, float* __restrict__ partials) {
    int tid = threadIdx.x;
    int sl = tid & 15;                               // lane within 16-group
    int grp = (blockIdx.x * 256 + tid) >> 4;         // global 16-group id
    int ngrp = gridDim.x * 16;
    // W2 coefficients for this lane's 4 dims: W2 is [64][2] row-major
    float2 wa = *(const float2*)&W2[(sl * 4 + 0) * 2];
    float2 wb = *(const float2*)&W2[(sl * 4 + 1) * 2];
    float2 wc = *(const float2*)&W2[(sl * 4 + 2) * 2];
    float2 wd = *(const float2*)&W2[(sl * 4 + 3) * 2];
    float b20 = b2[0], b21 = b2[1];
    float sum = 0.f;
    for (int e = grp; e < NE; e += ngrp) {
        int ln = L[e], rn = R[e];
        float4 p = *(const float4*)&P[ln * HD + sl * 4];
        float4 q = *(const float4*)&Q[rn * HD + sl * 4];
        float v0 = fmaxf(p.x + q.x, 0.f);
        float v1 = fmaxf(p.y + q.y, 0.f);
        float v2 = fmaxf(p.z + q.z, 0.f);
        float v3 = fmaxf(p.w + q.w, 0.f);
        float t0 = v0 * wa.x + v1 * wb.x + v2 * wc.x + v3 * wd.x;
        float t1 = v0 * wa.y + v1 * wb.y + v2 * wc.y + v3 * wd.y;
        #pragma unroll
        for (int m = 1; m < 16; m <<= 1) {           // reduce within 16-group
            t0 += __shfl_xor(t0, m, 64);
            t1 += __shfl_xor(t1, m, 64);
        }
        if (sl == 0) {
            float l0 = t0 + b20, l1 = t1 + b21;
            float mx = fmaxf(l0, l1);
            float lse = mx + __logf(__expf(l0 - mx) + __expf(l1 - mx));
            float sel = label[e] ? l1 : l0;
            sum += lse - sel;
        }
    }
    __shared__ float red[256];
    red[tid] = sum;
    __syncthreads();
    for (int s = 128; s > 0; s >>= 1) {
        if (tid < s) red[tid] += red[tid + s];
        __syncthreads();
    }
    if (tid == 0) partials[blockIdx.x] = red[0];
}

// K6: reduce 2048 partials -> mean
__global__ __launch_bounds__(1024) void k_reduce(const float* __restrict__ partials, float* __restrict__ out) {
    __shared__ float sh[1024];
    int t = threadIdx.x;
    sh[t] = partials[t] + partials[t + 1024];
    __syncthreads();
    for (int s = 512; s > 0; s >>= 1) {
        if (t < s) sh[t] += sh[t + s];
        __syncthreads();
    }
    if (t == 0) out[0] = sh[0] / (float)NE;
}

extern "C" void kernel_launch(void* const* d_in, const int* in_sizes, int n_in,
                              void* d_out, int out_size, void* d_ws, size_t ws_size,
                              hipStream_t stream) {
    const float* x     = (const float*)d_in[0];
    const float* adj   = (const float*)d_in[1];
    const int*   L     = (const int*)d_in[2];
    const int*   R     = (const int*)d_in[3];
    const int*   label = (const int*)d_in[4];
    const float* W     = (const float*)d_in[5];
    const float* a1    = (const float*)d_in[6];
    const float* a2    = (const float*)d_in[7];
    const float* W1    = (const float*)d_in[8];
    const float* b1    = (const float*)d_in[9];
    const float* W2    = (const float*)d_in[10];
    const float* b2    = (const float*)d_in[11];

    char* ws = (char*)d_ws;
    float* Wt       = (float*)(ws + 0);         //  131072 B (dead after k_wh)
    float* Wh       = (float*)(ws + 131072);    //  786432 B
    float* s1       = (float*)(ws + 917504);    //   98304 B
    float* s2       = (float*)(ws + 1015808);   //   98304 B
    int*   cnt      = (int*)  (ws + 1114112);   //   12288 B
    int*   nbr      = (int*)  (ws + 1126400);   // 1179648 B
    float* emb      = (float*)(ws + 2306048);   //  786432 B
    float* P        = (float*)(ws + 3092480);   //  786432 B
    float* Q        = (float*)(ws + 3878912);   //  786432 B -> end 4665344
    float* partials = (float*)(ws + 0);         // aliases Wt (dead by k_cls), 8192 B

    k_transpose_w<<<(FEAT * HD + 255) / 256, 256, 0, stream>>>(W, Wt);
    k_wh<<<NN / WH_ROWS, 64, 0, stream>>>(x, Wt, a1, a2, Wh, s1, s2);
    k_nbr<<<NN, 64, 0, stream>>>(adj, nbr, cnt);
    k_attn<<<NN / 4, 256, 0, stream>>>(Wh, s1, s2, nbr, cnt, emb);
    k_pq<<<NN, 64, 0, stream>>>(emb, W1, b1, P, Q);
    k_cls<<<K5_BLOCKS, 256, 0, stream>>>(P, Q, L, R, label, W2, b2, partials);
    k_reduce<<<1, 1024, 0, stream>>>(partials, (float*)d_out);
}

// Round 3
// 68.842 us; speedup vs baseline: 1.4926x; 1.2167x over previous
//
#include <hip/hip_runtime.h>
#include <math.h>

#define NN 3072
#define FEAT 512
#define NH 8
#define ND 8
#define HD 64           // NH*ND
#define NE 100000
#define NC 2
#define ALPHA 0.2f
#define CAP 96          // max neighbors per row (mean ~7)
#define K5_BLOCKS 2048

// K1: nbr compaction (all 3072 blocks) + W transpose piggybacked on first 512 blocks.
// Transpose: Wt[f*HD + (h*8+d)] = W[h*FEAT*ND + f*ND + d]
__global__ __launch_bounds__(64) void k_pre(const float* __restrict__ adj, const float* __restrict__ W,
                                            int* __restrict__ nbr, int* __restrict__ cnt,
                                            float* __restrict__ Wt) {
    int i = blockIdx.x;
    int lane = threadIdx.x;
    if (i < (FEAT * HD) / 64) {        // 512 blocks x 64 lanes = 32768 elements
        int idx = i * 64 + lane;
        int f = idx >> 6, hd = idx & 63;
        Wt[idx] = W[(hd >> 3) * FEAT * ND + f * ND + (hd & 7)];
    }
    unsigned long long lmask = (1ull << lane) - 1ull;
    int base = 0;
    for (int j0 = 0; j0 < NN; j0 += 256) {
        float4 v = *(const float4*)&adj[(size_t)i * NN + j0 + lane * 4];
        #pragma unroll
        for (int k = 0; k < 4; ++k) {
            float vk = k == 0 ? v.x : k == 1 ? v.y : k == 2 ? v.z : v.w;
            bool nz = vk > 0.f;
            unsigned long long m = __ballot(nz);
            if (nz) {
                int pos = base + __popcll(m & lmask);
                if (pos < CAP) nbr[i * CAP + pos] = j0 + lane * 4 + k;
            }
            base += __popcll(m);
        }
    }
    if (lane == 0) cnt[i] = base < CAP ? base : CAP;
}

// K2: Wh = x @ Wt  (M=3072, N=64, K=512), split-K across 4 waves per block.
//     Block: 256 threads / 4 waves; 4 rows per block; wave w covers f in [w*128,(w+1)*128).
__global__ __launch_bounds__(256) void k_wh(const float* __restrict__ x, const float* __restrict__ Wt,
                                            const float* __restrict__ a1, const float* __restrict__ a2,
                                            float* __restrict__ Wh, float* __restrict__ s1,
                                            float* __restrict__ s2) {
    __shared__ float xs[4][FEAT];
    __shared__ float part[4][4][HD];
    int n0 = blockIdx.x * 4;
    int tid = threadIdx.x;
    for (int idx = tid; idx < 4 * FEAT; idx += 256) {
        int r = idx >> 9, f = idx & (FEAT - 1);
        xs[r][f] = x[(n0 + r) * FEAT + f];
    }
    __syncthreads();
    int w = tid >> 6, l = tid & 63;
    int f0 = w * (FEAT / 4);
    float acc0 = 0.f, acc1 = 0.f, acc2 = 0.f, acc3 = 0.f;
    #pragma unroll 8
    for (int f = 0; f < FEAT / 4; ++f) {
        float wt = Wt[(f0 + f) * HD + l];
        acc0 = fmaf(xs[0][f0 + f], wt, acc0);
        acc1 = fmaf(xs[1][f0 + f], wt, acc1);
        acc2 = fmaf(xs[2][f0 + f], wt, acc2);
        acc3 = fmaf(xs[3][f0 + f], wt, acc3);
    }
    part[w][0][l] = acc0;
    part[w][1][l] = acc1;
    part[w][2][l] = acc2;
    part[w][3][l] = acc3;
    __syncthreads();
    // wave w finalizes row n0+w
    int n = n0 + w;
    float v = part[0][w][l] + part[1][w][l] + part[2][w][l] + part[3][w][l];
    Wh[n * HD + l] = v;
    float t1 = v * a1[l];
    float t2 = v * a2[l];
    for (int m = 1; m < 8; m <<= 1) {
        t1 += __shfl_xor(t1, m, 64);
        t2 += __shfl_xor(t2, m, 64);
    }
    if ((l & 7) == 0) {
        int h = l >> 3;
        s1[h * NN + n] = t1;
        s2[h * NN + n] = t2;
    }
}

// K3: per-row wave: online softmax over neighbors, weighted Wh sum, ELU -> emb (in LDS),
//     then fused P/Q: P[n]=emb@W1_top+b1, Q[n]=emb@W1_bot.
__global__ __launch_bounds__(256) void k_attn_pq(const float* __restrict__ Wh, const float* __restrict__ s1,
                                                 const float* __restrict__ s2, const int* __restrict__ nbr,
                                                 const int* __restrict__ cnt, const float* __restrict__ W1,
                                                 const float* __restrict__ b1, float* __restrict__ P,
                                                 float* __restrict__ Q) {
    __shared__ float es[4][HD];
    int wid = threadIdx.x >> 6;
    int lane = threadIdx.x & 63;   // lane = h*8+d
    int i = blockIdx.x * 4 + wid;
    int h = lane >> 3;
    float s1i = s1[h * NN + i];
    int ni = cnt[i];
    float m = -INFINITY, denom = 0.f, acc = 0.f;
    for (int k = 0; k < ni; ++k) {
        int j = nbr[i * CAP + k];
        float ev = s1i + s2[h * NN + j];
        ev = ev > 0.f ? ev : ALPHA * ev;
        float mn = fmaxf(m, ev);
        float c = __expf(m - mn);      // exp(-inf)=0 on first iter
        float p = __expf(ev - mn);
        denom = denom * c + p;
        acc = acc * c + p * Wh[j * HD + lane];
        m = mn;
    }
    float o = acc / denom;
    o = o > 0.f ? o : expm1f(o);       // ELU
    es[wid][lane] = o;
    __syncthreads();
    float p = b1[lane], q = 0.f;
    #pragma unroll 8
    for (int k = 0; k < HD; ++k) {
        float e = es[wid][k];
        p = fmaf(e, W1[k * HD + lane], p);
        q = fmaf(e, W1[(HD + k) * HD + lane], q);
    }
    P[i * HD + lane] = p;
    Q[i * HD + lane] = q;
}

// K4: 16 lanes per edge, float4 loads. h1 = relu(P[L]+Q[R]); logits = h1@W2+b2; nll.
__global__ __launch_bounds__(256) void k_cls(const float* __restrict__ P, const float* __restrict__ Q,
                                             const int* __restrict__ L, const int* __restrict__ R,
                                             const int* __restrict__ label, const float* __restrict__ W2,
                                             const float* __restrict__ b2, float* __restrict__ partials) {
    int tid = threadIdx.x;
    int sl = tid & 15;                               // lane within 16-group
    int grp = (blockIdx.x * 256 + tid) >> 4;         // global 16-group id
    int ngrp = gridDim.x * 16;
    float2 wa = *(const float2*)&W2[(sl * 4 + 0) * 2];
    float2 wb = *(const float2*)&W2[(sl * 4 + 1) * 2];
    float2 wc = *(const float2*)&W2[(sl * 4 + 2) * 2];
    float2 wd = *(const float2*)&W2[(sl * 4 + 3) * 2];
    float b20 = b2[0], b21 = b2[1];
    float sum = 0.f;
    for (int e = grp; e < NE; e += ngrp) {
        int ln = L[e], rn = R[e];
        float4 p = *(const float4*)&P[ln * HD + sl * 4];
        float4 q = *(const float4*)&Q[rn * HD + sl * 4];
        float v0 = fmaxf(p.x + q.x, 0.f);
        float v1 = fmaxf(p.y + q.y, 0.f);
        float v2 = fmaxf(p.z + q.z, 0.f);
        float v3 = fmaxf(p.w + q.w, 0.f);
        float t0 = v0 * wa.x + v1 * wb.x + v2 * wc.x + v3 * wd.x;
        float t1 = v0 * wa.y + v1 * wb.y + v2 * wc.y + v3 * wd.y;
        #pragma unroll
        for (int m = 1; m < 16; m <<= 1) {
            t0 += __shfl_xor(t0, m, 64);
            t1 += __shfl_xor(t1, m, 64);
        }
        if (sl == 0) {
            float l0 = t0 + b20, l1 = t1 + b21;
            float mx = fmaxf(l0, l1);
            float lse = mx + __logf(__expf(l0 - mx) + __expf(l1 - mx));
            float sel = label[e] ? l1 : l0;
            sum += lse - sel;
        }
    }
    __shared__ float red[256];
    red[tid] = sum;
    __syncthreads();
    for (int s = 128; s > 0; s >>= 1) {
        if (tid < s) red[tid] += red[tid + s];
        __syncthreads();
    }
    if (tid == 0) partials[blockIdx.x] = red[0];
}

// K5: reduce 2048 partials -> mean
__global__ __launch_bounds__(1024) void k_reduce(const float* __restrict__ partials, float* __restrict__ out) {
    __shared__ float sh[1024];
    int t = threadIdx.x;
    sh[t] = partials[t] + partials[t + 1024];
    __syncthreads();
    for (int s = 512; s > 0; s >>= 1) {
        if (t < s) sh[t] += sh[t + s];
        __syncthreads();
    }
    if (t == 0) out[0] = sh[0] / (float)NE;
}

extern "C" void kernel_launch(void* const* d_in, const int* in_sizes, int n_in,
                              void* d_out, int out_size, void* d_ws, size_t ws_size,
                              hipStream_t stream) {
    const float* x     = (const float*)d_in[0];
    const float* adj   = (const float*)d_in[1];
    const int*   L     = (const int*)d_in[2];
    const int*   R     = (const int*)d_in[3];
    const int*   label = (const int*)d_in[4];
    const float* W     = (const float*)d_in[5];
    const float* a1    = (const float*)d_in[6];
    const float* a2    = (const float*)d_in[7];
    const float* W1    = (const float*)d_in[8];
    const float* b1    = (const float*)d_in[9];
    const float* W2    = (const float*)d_in[10];
    const float* b2    = (const float*)d_in[11];

    char* ws = (char*)d_ws;
    float* Wt       = (float*)(ws + 0);         //  131072 B (dead after k_wh)
    float* Wh       = (float*)(ws + 131072);    //  786432 B
    float* s1       = (float*)(ws + 917504);    //   98304 B
    float* s2       = (float*)(ws + 1015808);   //   98304 B
    int*   cnt      = (int*)  (ws + 1114112);   //   12288 B
    int*   nbr      = (int*)  (ws + 1126400);   // 1179648 B
    float* P        = (float*)(ws + 2306048);   //  786432 B
    float* Q        = (float*)(ws + 3092480);   //  786432 B -> end 3878912
    float* partials = (float*)(ws + 0);         // aliases Wt (dead by k_cls), 8192 B

    k_pre<<<NN, 64, 0, stream>>>(adj, W, nbr, cnt, Wt);
    k_wh<<<NN / 4, 256, 0, stream>>>(x, Wt, a1, a2, Wh, s1, s2);
    k_attn_pq<<<NN / 4, 256, 0, stream>>>(Wh, s1, s2, nbr, cnt, W1, b1, P, Q);
    k_cls<<<K5_BLOCKS, 256, 0, stream>>>(P, Q, L, R, label, W2, b2, partials);
    k_reduce<<<1, 1024, 0, stream>>>(partials, (float*)d_out);
}

// Round 4
// 38.393 us; speedup vs baseline: 2.6763x; 1.7931x over previous
//
#include <hip/hip_runtime.h>
#include <math.h>

#define NN 3072
#define FEAT 512
#define HD 64           // 8 heads x 8 dims
#define NE 100000
#define ALPHA 0.2f
#define CAP 96          // max neighbors per row (mean ~7)
#define CAPP 97         // padded for LDS bank spread
#define K5_BLOCKS 2048

// K1: neighbor compaction with full-row register prefetch; W transpose piggybacked
// on the first 512 blocks. Wt2 layout: float4-friendly [FEAT/4][HD][4]:
//   Wt2[((f>>2)*HD + hd)*4 + (f&3)] = W[(hd>>3)*FEAT*8 + f*8 + (hd&7)]
__global__ __launch_bounds__(64) void k_pre(const float* __restrict__ adj, const float* __restrict__ W,
                                            int* __restrict__ nbr, int* __restrict__ cnt,
                                            float* __restrict__ Wt2) {
    int i = blockIdx.x;
    int lane = threadIdx.x;
    if (i < (FEAT * HD) / 64) {
        int idx = i * 64 + lane;
        int f = idx >> 6, hd = idx & 63;
        Wt2[((f >> 2) * HD + hd) * 4 + (f & 3)] = W[(hd >> 3) * FEAT * 8 + f * 8 + (hd & 7)];
    }
    const float4* row = (const float4*)&adj[(size_t)i * NN];
    float4 v[12];
    #pragma unroll
    for (int c = 0; c < 12; ++c) v[c] = row[c * 64 + lane];   // all 12 loads in flight
    unsigned long long lmask = (1ull << lane) - 1ull;
    int base = 0;
    #pragma unroll
    for (int c = 0; c < 12; ++c) {
        #pragma unroll
        for (int k = 0; k < 4; ++k) {
            float vk = k == 0 ? v[c].x : k == 1 ? v[c].y : k == 2 ? v[c].z : v[c].w;
            bool nz = vk > 0.f;
            unsigned long long m = __ballot(nz);
            if (nz) {
                int pos = base + __popcll(m & lmask);
                if (pos < CAP) nbr[i * CAP + pos] = c * 256 + lane * 4 + k;
            }
            base += __popcll(m);
        }
    }
    if (lane == 0) cnt[i] = base < CAP ? base : CAP;
}

// K2: Wh = x @ W^T slices (M=3072,N=64,K=512). 512 threads / 8 waves per block,
// 4 rows per block, K split 8 ways; float4 Wt2 loads (16B/lane coalesced).
// Also s1t[n*8+h] = Wh[n].a1[h], s2t likewise ([N][8] layout for 32B gathers).
__global__ __launch_bounds__(512) void k_wh(const float* __restrict__ x, const float4* __restrict__ Wt2v,
                                            const float* __restrict__ a1, const float* __restrict__ a2,
                                            float* __restrict__ Wh, float* __restrict__ s1t,
                                            float* __restrict__ s2t) {
    __shared__ float4 xs4[4][FEAT / 4];
    __shared__ float part[8][4][HD];
    int n0 = blockIdx.x * 4;
    int tid = threadIdx.x;
    {   // stage 4 rows of x: one float4 per thread, coalesced
        int r = tid >> 7, fq = tid & 127;
        xs4[r][fq] = ((const float4*)x)[(n0 + r) * (FEAT / 4) + fq];
    }
    __syncthreads();
    int w = tid >> 6, l = tid & 63;
    float acc0 = 0.f, acc1 = 0.f, acc2 = 0.f, acc3 = 0.f;
    #pragma unroll 4
    for (int i4 = 0; i4 < 16; ++i4) {
        int fq = w * 16 + i4;                 // float4 index along K
        float4 wt = Wt2v[fq * HD + l];
        float4 x0 = xs4[0][fq], x1 = xs4[1][fq], x2 = xs4[2][fq], x3 = xs4[3][fq];
        acc0 = fmaf(x0.x, wt.x, fmaf(x0.y, wt.y, fmaf(x0.z, wt.z, fmaf(x0.w, wt.w, acc0))));
        acc1 = fmaf(x1.x, wt.x, fmaf(x1.y, wt.y, fmaf(x1.z, wt.z, fmaf(x1.w, wt.w, acc1))));
        acc2 = fmaf(x2.x, wt.x, fmaf(x2.y, wt.y, fmaf(x2.z, wt.z, fmaf(x2.w, wt.w, acc2))));
        acc3 = fmaf(x3.x, wt.x, fmaf(x3.y, wt.y, fmaf(x3.z, wt.z, fmaf(x3.w, wt.w, acc3))));
    }
    part[w][0][l] = acc0;
    part[w][1][l] = acc1;
    part[w][2][l] = acc2;
    part[w][3][l] = acc3;
    __syncthreads();
    if (w < 4) {                              // wave w finalizes row n0+w
        int n = n0 + w;
        float v = 0.f;
        #pragma unroll
        for (int w2 = 0; w2 < 8; ++w2) v += part[w2][w][l];   // fixed order: deterministic
        Wh[n * HD + l] = v;
        float t1 = v * a1[l];
        float t2 = v * a2[l];
        for (int m = 1; m < 8; m <<= 1) {
            t1 += __shfl_xor(t1, m, 64);
            t2 += __shfl_xor(t2, m, 64);
        }
        if ((l & 7) == 0) {
            int h = l >> 3;
            s1t[n * 8 + h] = t1;
            s2t[n * 8 + h] = t2;
        }
    }
}

// K3: attention + ELU + fused P/Q. Wave per row; lane = h*8+d.
// Phase A: logits in parallel across lanes (k strided by d) -> LDS, shfl-max.
// Phase B: independent exps + Wh gathers, cheap add chains. Then P/Q MLP.
__global__ __launch_bounds__(256) void k_attn_pq(const float* __restrict__ Wh, const float* __restrict__ s1t,
                                                 const float* __restrict__ s2t, const int* __restrict__ nbr,
                                                 const int* __restrict__ cnt, const float* __restrict__ W1,
                                                 const float* __restrict__ b1, float* __restrict__ P,
                                                 float* __restrict__ Q) {
    __shared__ int   jbuf[4][CAP];
    __shared__ float ebuf[4][8][CAPP];
    __shared__ float es[4][HD];
    int wid = threadIdx.x >> 6;
    int lane = threadIdx.x & 63;
    int i = blockIdx.x * 4 + wid;
    int h = lane >> 3, d = lane & 7;
    int ni = cnt[i];
    for (int k = lane; k < CAP; k += 64)
        if (k < ni) jbuf[wid][k] = nbr[i * CAP + k];
    __syncthreads();
    float s1i = s1t[i * 8 + h];
    float mloc = -INFINITY;
    for (int k = d; k < ni; k += 8) {
        int j = jbuf[wid][k];
        float ev = s1i + s2t[j * 8 + h];
        ev = ev > 0.f ? ev : ALPHA * ev;
        ebuf[wid][h][k] = ev;
        mloc = fmaxf(mloc, ev);
    }
    mloc = fmaxf(mloc, __shfl_xor(mloc, 1, 8));   // max over d within head group
    mloc = fmaxf(mloc, __shfl_xor(mloc, 2, 8));
    mloc = fmaxf(mloc, __shfl_xor(mloc, 4, 8));
    __syncthreads();
    float denom = 0.f, acc = 0.f;
    for (int k = 0; k < ni; ++k) {
        float p = __expf(ebuf[wid][h][k] - mloc);
        denom += p;
        acc = fmaf(p, Wh[jbuf[wid][k] * HD + lane], acc);
    }
    float o = acc / denom;
    o = o > 0.f ? o : expm1f(o);                  // ELU
    es[wid][lane] = o;
    __syncthreads();
    float p = b1[lane], q = 0.f;
    #pragma unroll 8
    for (int k = 0; k < HD; ++k) {
        float e = es[wid][k];
        p = fmaf(e, W1[k * HD + lane], p);
        q = fmaf(e, W1[(HD + k) * HD + lane], q);
    }
    P[i * HD + lane] = p;
    Q[i * HD + lane] = q;
}

// K4: 16 lanes per edge, float4 loads. h1 = relu(P[L]+Q[R]); logits = h1@W2+b2; nll.
__global__ __launch_bounds__(256) void k_cls(const float* __restrict__ P, const float* __restrict__ Q,
                                             const int* __restrict__ L, const int* __restrict__ R,
                                             const int* __restrict__ label, const float* __restrict__ W2,
                                             const float* __restrict__ b2, float* __restrict__ partials) {
    int tid = threadIdx.x;
    int sl = tid & 15;
    int grp = (blockIdx.x * 256 + tid) >> 4;
    int ngrp = gridDim.x * 16;
    float2 wa = *(const float2*)&W2[(sl * 4 + 0) * 2];
    float2 wb = *(const float2*)&W2[(sl * 4 + 1) * 2];
    float2 wc = *(const float2*)&W2[(sl * 4 + 2) * 2];
    float2 wd = *(const float2*)&W2[(sl * 4 + 3) * 2];
    float b20 = b2[0], b21 = b2[1];
    float sum = 0.f;
    for (int e = grp; e < NE; e += ngrp) {
        int ln = L[e], rn = R[e];
        float4 p = *(const float4*)&P[ln * HD + sl * 4];
        float4 q = *(const float4*)&Q[rn * HD + sl * 4];
        float v0 = fmaxf(p.x + q.x, 0.f);
        float v1 = fmaxf(p.y + q.y, 0.f);
        float v2 = fmaxf(p.z + q.z, 0.f);
        float v3 = fmaxf(p.w + q.w, 0.f);
        float t0 = v0 * wa.x + v1 * wb.x + v2 * wc.x + v3 * wd.x;
        float t1 = v0 * wa.y + v1 * wb.y + v2 * wc.y + v3 * wd.y;
        #pragma unroll
        for (int m = 1; m < 16; m <<= 1) {
            t0 += __shfl_xor(t0, m, 64);
            t1 += __shfl_xor(t1, m, 64);
        }
        if (sl == 0) {
            float l0 = t0 + b20, l1 = t1 + b21;
            float mx = fmaxf(l0, l1);
            float lse = mx + __logf(__expf(l0 - mx) + __expf(l1 - mx));
            float sel = label[e] ? l1 : l0;
            sum += lse - sel;
        }
    }
    __shared__ float red[256];
    red[tid] = sum;
    __syncthreads();
    for (int s = 128; s > 0; s >>= 1) {
        if (tid < s) red[tid] += red[tid + s];
        __syncthreads();
    }
    if (tid == 0) partials[blockIdx.x] = red[0];
}

// K5: reduce 2048 partials -> mean
__global__ __launch_bounds__(1024) void k_reduce(const float* __restrict__ partials, float* __restrict__ out) {
    __shared__ float sh[1024];
    int t = threadIdx.x;
    sh[t] = partials[t] + partials[t + 1024];
    __syncthreads();
    for (int s = 512; s > 0; s >>= 1) {
        if (t < s) sh[t] += sh[t + s];
        __syncthreads();
    }
    if (t == 0) out[0] = sh[0] / (float)NE;
}

extern "C" void kernel_launch(void* const* d_in, const int* in_sizes, int n_in,
                              void* d_out, int out_size, void* d_ws, size_t ws_size,
                              hipStream_t stream) {
    const float* x     = (const float*)d_in[0];
    const float* adj   = (const float*)d_in[1];
    const int*   L     = (const int*)d_in[2];
    const int*   R     = (const int*)d_in[3];
    const int*   label = (const int*)d_in[4];
    const float* W     = (const float*)d_in[5];
    const float* a1    = (const float*)d_in[6];
    const float* a2    = (const float*)d_in[7];
    const float* W1    = (const float*)d_in[8];
    const float* b1    = (const float*)d_in[9];
    const float* W2    = (const float*)d_in[10];
    const float* b2    = (const float*)d_in[11];

    char* ws = (char*)d_ws;
    float* Wt2      = (float*)(ws + 0);         //  131072 B (dead after k_wh)
    float* Wh       = (float*)(ws + 131072);    //  786432 B
    float* s1t      = (float*)(ws + 917504);    //   98304 B   [N][8]
    float* s2t      = (float*)(ws + 1015808);   //   98304 B   [N][8]
    int*   cnt      = (int*)  (ws + 1114112);   //   12288 B
    int*   nbr      = (int*)  (ws + 1126400);   // 1179648 B
    float* P        = (float*)(ws + 2306048);   //  786432 B
    float* Q        = (float*)(ws + 3092480);   //  786432 B -> end 3878912
    float* partials = (float*)(ws + 0);         // aliases Wt2 (dead by k_cls), 8192 B

    k_pre<<<NN, 64, 0, stream>>>(adj, W, nbr, cnt, Wt2);
    k_wh<<<NN / 4, 512, 0, stream>>>(x, (const float4*)Wt2, a1, a2, Wh, s1t, s2t);
    k_attn_pq<<<NN / 4, 256, 0, stream>>>(Wh, s1t, s2t, nbr, cnt, W1, b1, P, Q);
    k_cls<<<K5_BLOCKS, 256, 0, stream>>>(P, Q, L, R, label, W2, b2, partials);
    k_reduce<<<1, 1024, 0, stream>>>(partials, (float*)d_out);
}